// Round 3
// baseline (786.647 us; speedup 1.0000x reference)
//
#include <hip/hip_runtime.h>
#include <hip/hip_bf16.h>

typedef __bf16 bf16_t;
typedef bf16_t bf16x8 __attribute__((ext_vector_type(8)));
typedef float f32x4 __attribute__((ext_vector_type(4)));

// ---------------------------------------------------------------------------
// K_PREP: fused { Wg1 transpose->bf16, gate GEMV, mask compaction } in one
// dispatch. grid 1024 x 256 thr, switched on blockIdx ranges.
//   bid [0,256):    Wg1T tile (k-tile = bid&15, e-tile = bid>>4)
//   bid [256,768):  g[b][e] = Ct[b,:]@Wg2[:,e]+bias (b = (bid-256)>>1, e-half)
//   bid [768,1024): per-batch unmasked-row compaction (wave 0)
// ---------------------------------------------------------------------------
__global__ __launch_bounds__(256) void k_prep(const float* __restrict__ Wg1,
                                              bf16_t* __restrict__ Wg1T,
                                              const float* __restrict__ Ct,
                                              const float* __restrict__ Wg2,
                                              const float* __restrict__ bias,
                                              float* __restrict__ g,
                                              const int* __restrict__ mask,
                                              int* __restrict__ idx,
                                              int* __restrict__ nnz) {
    const int bid = blockIdx.x;
    const int t   = threadIdx.x;
    if (bid < 256) {
        __shared__ float tile[32][33];
        const int k0 = (bid & 15) << 5;
        const int e0 = (bid >> 4) << 5;
        const int tx = t & 31;
        const int ty = t >> 5;              // 0..7
        #pragma unroll
        for (int i = 0; i < 32; i += 8)
            tile[ty + i][tx] = Wg1[(k0 + ty + i) * 512 + e0 + tx];
        __syncthreads();
        #pragma unroll
        for (int i = 0; i < 32; i += 8)
            Wg1T[(e0 + ty + i) * 512 + k0 + tx] = (bf16_t)tile[tx][ty + i];
    } else if (bid < 768) {
        __shared__ float q[512];
        const int gb = bid - 256;
        const int b  = gb >> 1;
        q[t]       = Ct[b * 512 + t];
        q[t + 256] = Ct[b * 512 + t + 256];
        __syncthreads();
        const int e = ((gb & 1) << 8) + t;
        float acc = bias[e];
        #pragma unroll 16
        for (int k = 0; k < 512; ++k)
            acc = fmaf(q[k], Wg2[k * 512 + e], acc);
        g[b * 512 + e] = acc;
    } else {
        const int b = bid - 768;
        if (t < 64) {                        // wave 0 only
            const int lane = t;
            int base = 0;
            #pragma unroll
            for (int c = 0; c < 8; ++c) {
                const int l = (c << 6) + lane;
                const int v = mask[(b << 9) + l];
                const unsigned long long m = __ballot(v != 0);
                const int rank = __popcll(m & ((1ull << lane) - 1ull));
                if (v) idx[(b << 9) + base + rank] = l;
                base += __popcll(m);
            }
            if (lane == 0) nnz[b] = base;
        }
    }
}

// ---------------------------------------------------------------------------
// K2: compacted-row GEMM + fused relu/w0 reduction epilogue.
// v3 (round-2 post-mortem: WRITE_SIZE 21.8MB = register spill; fix = cut
// pressure, kill LDS/barriers entirely):
//   - M=32 rows x N=512 x K=512 per 4-wave block; wave owns 128 cols.
//   - acc[2][8] = 64 AGPR (half of v2). NO A-staging: each lane loads its 2
//     fragment rows straight from global C (16 rows x 128B full lines per
//     instr pair) and converts fp32->bf16 in regs. C re-read 4x from hot L2.
//   - B fragments from L2-resident Wg1T, consumed in 2 groups of 4 ni
//     (live bfr = 32 regs). #pragma unroll 2 on kc. Peak VGPR ~90 under the
//     (256,3) cap of ~106 -> no spill, 12 waves/CU, zero K-loop barriers.
//   - Epilogue LDS only (1KB sred). Single writer per score row.
// ---------------------------------------------------------------------------
__global__ __launch_bounds__(256, 3) void k_score(const float* __restrict__ C,
                                                  const bf16_t* __restrict__ Wg1T,
                                                  const float* __restrict__ g,
                                                  const float* __restrict__ Wg0,
                                                  const int* __restrict__ idx,
                                                  const int* __restrict__ nnz,
                                                  float* __restrict__ score) {
    __shared__ float sred[4][32];

    const int t    = threadIdx.x;
    const int lane = t & 63;
    const int wave = t >> 6;
    const int quad = lane >> 4;
    const int l15  = lane & 15;

    const int bid  = blockIdx.x;        // 4096 = 256 b x 16 tiles of 32 rows
    const int b    = bid >> 4;
    const int tile = bid & 15;
    const int nb   = nnz[b];
    if (tile * 32 >= nb) return;        // uniform early exit

    // per-lane A row indices (clamped -> duplicate rows compute identical)
    const int j0  = tile * 32 + l15;
    const int j1  = j0 + 16;
    const int rs0 = idx[(b << 9) + (j0 < nb ? j0 : nb - 1)];
    const int rs1 = idx[(b << 9) + (j1 < nb ? j1 : nb - 1)];

    const float* Cb  = C + ((size_t)b << 18);
    const float* Ab0 = Cb + (size_t)rs0 * 512 + (quad << 3);
    const float* Ab1 = Cb + (size_t)rs1 * 512 + (quad << 3);
    const bf16_t* Bb = Wg1T + (((wave << 7) + l15) << 9) + (quad << 3);

    f32x4 acc[2][8] = {};

    #pragma unroll 2
    for (int kc = 0; kc < 16; ++kc) {
        // ---- A fragments: 2 rows x 8 k, fp32 global -> bf16 regs ----
        const float4 a00 = *reinterpret_cast<const float4*>(Ab0 + (kc << 5));
        const float4 a01 = *reinterpret_cast<const float4*>(Ab0 + (kc << 5) + 4);
        const float4 a10 = *reinterpret_cast<const float4*>(Ab1 + (kc << 5));
        const float4 a11 = *reinterpret_cast<const float4*>(Ab1 + (kc << 5) + 4);
        union { bf16_t h[8]; bf16x8 v; } ua0, ua1;
        ua0.h[0] = (bf16_t)a00.x; ua0.h[1] = (bf16_t)a00.y;
        ua0.h[2] = (bf16_t)a00.z; ua0.h[3] = (bf16_t)a00.w;
        ua0.h[4] = (bf16_t)a01.x; ua0.h[5] = (bf16_t)a01.y;
        ua0.h[6] = (bf16_t)a01.z; ua0.h[7] = (bf16_t)a01.w;
        ua1.h[0] = (bf16_t)a10.x; ua1.h[1] = (bf16_t)a10.y;
        ua1.h[2] = (bf16_t)a10.z; ua1.h[3] = (bf16_t)a10.w;
        ua1.h[4] = (bf16_t)a11.x; ua1.h[5] = (bf16_t)a11.y;
        ua1.h[6] = (bf16_t)a11.z; ua1.h[7] = (bf16_t)a11.w;

        // ---- B group 0: ni 0..3 ----
        bf16x8 bfr[4];
        #pragma unroll
        for (int ni = 0; ni < 4; ++ni)
            bfr[ni] = *reinterpret_cast<const bf16x8*>(
                Bb + ((size_t)ni << 13) + (kc << 5));
        #pragma unroll
        for (int ni = 0; ni < 4; ++ni) {
            acc[0][ni] = __builtin_amdgcn_mfma_f32_16x16x32_bf16(
                ua0.v, bfr[ni], acc[0][ni], 0, 0, 0);
            acc[1][ni] = __builtin_amdgcn_mfma_f32_16x16x32_bf16(
                ua1.v, bfr[ni], acc[1][ni], 0, 0, 0);
        }
        // ---- B group 1: ni 4..7 ----
        #pragma unroll
        for (int ni = 0; ni < 4; ++ni)
            bfr[ni] = *reinterpret_cast<const bf16x8*>(
                Bb + ((size_t)(ni + 4) << 13) + (kc << 5));
        #pragma unroll
        for (int ni = 0; ni < 4; ++ni) {
            acc[0][ni + 4] = __builtin_amdgcn_mfma_f32_16x16x32_bf16(
                ua0.v, bfr[ni], acc[0][ni + 4], 0, 0, 0);
            acc[1][ni + 4] = __builtin_amdgcn_mfma_f32_16x16x32_bf16(
                ua1.v, bfr[ni], acc[1][ni + 4], 0, 0, 0);
        }
    }

    // ---- epilogue: relu(u+g)*w0, reduce over this wave's 128 n ----
    float rsum[8];
    #pragma unroll
    for (int i = 0; i < 8; ++i) rsum[i] = 0.f;
    #pragma unroll
    for (int ni = 0; ni < 8; ++ni) {
        const int n  = (wave << 7) + (ni << 4) + l15;    // D col = lane&15
        const float gv = g[(b << 9) + n];
        const float w0 = Wg0[n];
        #pragma unroll
        for (int mi = 0; mi < 2; ++mi)
            #pragma unroll
            for (int r = 0; r < 4; ++r) {                // D row = quad*4 + r
                const float u = fmaxf(acc[mi][ni][r] + gv, 0.f);
                rsum[mi * 4 + r] = fmaf(u, w0, rsum[mi * 4 + r]);
            }
    }
    #pragma unroll
    for (int i = 0; i < 8; ++i) {
        float v = rsum[i];
        v += __shfl_xor(v, 1);
        v += __shfl_xor(v, 2);
        v += __shfl_xor(v, 4);
        v += __shfl_xor(v, 8);
        rsum[i] = v;
    }
    if (l15 == 0) {
        #pragma unroll
        for (int mi = 0; mi < 2; ++mi)
            #pragma unroll
            for (int r = 0; r < 4; ++r)
                sred[wave][mi * 16 + quad * 4 + r] = rsum[mi * 4 + r];
    }
    __syncthreads();
    if (t < 32) {
        const int j = tile * 32 + t;
        if (j < nb) {
            const float sc = sred[0][t] + sred[1][t] + sred[2][t] + sred[3][t];
            score[(b << 9) + idx[(b << 9) + j]] = sc;    // single writer
        }
    }
}

// ---------------------------------------------------------------------------
// K_POST: fused { entmax bisection (wave 0), support-only attn, out GEMV }.
// One block per batch (256 blocks x 256 thr). No atomics, no memsets:
// out row has a single writer block. X[b] (512KB) streamed once.
// ---------------------------------------------------------------------------
__global__ __launch_bounds__(256) void k_post(const float* __restrict__ score,
                                              const int* __restrict__ mask,
                                              const float* __restrict__ alpha,
                                              const float* __restrict__ C,
                                              const float* __restrict__ X,
                                              float* __restrict__ out) {
    __shared__ float sup_v[512];
    __shared__ int   sup_i[512];
    __shared__ int   s_n;
    __shared__ float attn_s[512];
    __shared__ f32x4 red[4][64];

    const int b = blockIdx.x;
    const int t = threadIdx.x;

    // ---- phase 1: entmax on wave 0 (lane holds 8 scores) ----
    if (t < 64) {
        const int lane = t;
        const float am1 = alpha[0] - 1.0f;
        const float inv = 1.0f / am1;
        const bool  sq  = fabsf(inv - 2.0f) < 1e-6f;   // alpha==1.5 -> u*u
        const float neg = -1e30f * am1;

        const float* sb = score + (b << 9);
        const int*   mb = mask  + (b << 9);
        float x[8];
        {
            const float4 v0 = *reinterpret_cast<const float4*>(sb + lane * 8);
            const float4 v1 = *reinterpret_cast<const float4*>(sb + lane * 8 + 4);
            const int4   m0 = *reinterpret_cast<const int4*>(mb + lane * 8);
            const int4   m1 = *reinterpret_cast<const int4*>(mb + lane * 8 + 4);
            x[0] = m0.x ? v0.x * am1 : neg; x[1] = m0.y ? v0.y * am1 : neg;
            x[2] = m0.z ? v0.z * am1 : neg; x[3] = m0.w ? v0.w * am1 : neg;
            x[4] = m1.x ? v1.x * am1 : neg; x[5] = m1.y ? v1.y * am1 : neg;
            x[6] = m1.z ? v1.z * am1 : neg; x[7] = m1.w ? v1.w * am1 : neg;
        }
        float m = x[0];
        #pragma unroll
        for (int j = 1; j < 8; ++j) m = fmaxf(m, x[j]);
        #pragma unroll
        for (int s = 1; s < 64; s <<= 1) m = fmaxf(m, __shfl_xor(m, s));

        float tau_lo = m - 1.0f;
        float dm = (m - powf(1.0f / 512.0f, am1)) - tau_lo;

        float f_lo;
        {
            float s = 0.f;
            #pragma unroll
            for (int j = 0; j < 8; ++j) {
                const float u = fmaxf(x[j] - tau_lo, 0.f);
                s += sq ? u * u : powf(u, inv);
            }
            #pragma unroll
            for (int sh = 1; sh < 64; sh <<= 1) s += __shfl_xor(s, sh);
            f_lo = s - 1.0f;
        }
        for (int it = 0; it < 50; ++it) {
            dm *= 0.5f;
            const float tau_m = tau_lo + dm;
            float s = 0.f;
            #pragma unroll
            for (int j = 0; j < 8; ++j) {
                const float u = fmaxf(x[j] - tau_m, 0.f);
                s += sq ? u * u : powf(u, inv);
            }
            #pragma unroll
            for (int sh = 1; sh < 64; sh <<= 1) s += __shfl_xor(s, sh);
            if ((s - 1.0f) * f_lo >= 0.f) tau_lo = tau_m;
        }
        const float tau = tau_lo + 0.5f * dm;
        float pj[8];
        float Z = 0.f;
        #pragma unroll
        for (int j = 0; j < 8; ++j) {
            const float u = fmaxf(x[j] - tau, 0.f);
            pj[j] = sq ? u * u : powf(u, inv);
            Z += pj[j];
        }
        #pragma unroll
        for (int sh = 1; sh < 64; sh <<= 1) Z += __shfl_xor(Z, sh);
        const float rz = 1.0f / Z;

        int base = 0;
        #pragma unroll
        for (int j = 0; j < 8; ++j) {
            const float pv = pj[j] * rz;
            const unsigned long long bm = __ballot(pv > 0.f);
            const int rank = __popcll(bm & ((1ull << lane) - 1ull));
            if (pv > 0.f) {
                sup_i[base + rank] = lane * 8 + j;
                sup_v[base + rank] = pv;
            }
            base += __popcll(bm);
        }
        if (lane == 0) s_n = base;
    }
    __syncthreads();

    // ---- phase 2: attn[e] = sum_j pv[j] * C[b, li[j], e] (support only) ----
    const int n = s_n;
    const float* Cb = C + ((size_t)b << 18);
    float a0 = 0.f, a1 = 0.f;
    int j = 0;
    for (; j + 4 <= n; j += 4) {
        #pragma unroll
        for (int u = 0; u < 4; ++u) {
            const float  w  = sup_v[j + u];
            const float* cr = Cb + ((size_t)sup_i[j + u] << 9);
            a0 = fmaf(w, cr[t], a0);
            a1 = fmaf(w, cr[t + 256], a1);
        }
    }
    for (; j < n; ++j) {
        const float  w  = sup_v[j];
        const float* cr = Cb + ((size_t)sup_i[j] << 9);
        a0 = fmaf(w, cr[t], a0);
        a1 = fmaf(w, cr[t + 256], a1);
    }
    attn_s[t]       = a0;
    attn_s[t + 256] = a1;
    __syncthreads();

    // ---- phase 3: out[b][d] = sum_e attn[e] * X[b][e][d], stream 512KB ----
    const int eg = t >> 6;               // 0..3 e-interleave group
    const int d4 = t & 63;               // float4 slot over d
    const float4* Xb = reinterpret_cast<const float4*>(X + ((size_t)b << 17));
    f32x4 a = {};
    #pragma unroll 8
    for (int e = eg; e < 512; e += 4) {
        const float  w = attn_s[e];
        const float4 v = Xb[e * 64 + d4];
        a[0] = fmaf(w, v.x, a[0]);
        a[1] = fmaf(w, v.y, a[1]);
        a[2] = fmaf(w, v.z, a[2]);
        a[3] = fmaf(w, v.w, a[3]);
    }
    red[eg][d4] = a;
    __syncthreads();
    if (t < 64) {
        const f32x4 s = red[0][t] + red[1][t] + red[2][t] + red[3][t];
        float4 o;
        o.x = s[0]; o.y = s[1]; o.z = s[2]; o.w = s[3];
        *reinterpret_cast<float4*>(out + (b << 8) + (t << 2)) = o;
    }
}

// ---------------------------------------------------------------------------
extern "C" void kernel_launch(void* const* d_in, const int* in_sizes, int n_in,
                              void* d_out, int out_size, void* d_ws, size_t ws_size,
                              hipStream_t stream) {
    const float* C_target = (const float*)d_in[0];
    const float* C        = (const float*)d_in[1];
    const float* X        = (const float*)d_in[2];
    const float* alpha    = (const float*)d_in[3];
    const int*   mask     = (const int*)  d_in[4];
    const float* Wg1      = (const float*)d_in[5];
    const float* Wg2      = (const float*)d_in[6];
    const float* Wg0      = (const float*)d_in[7];
    const float* bias     = (const float*)d_in[8];
    float* out = (float*)d_out;

    char* ws = (char*)d_ws;
    bf16_t* wg1t  = (bf16_t*)(ws);                       // 512 KB
    float*  g     = (float*)(ws + ( 512u << 10));        // 512 KB
    float*  score = (float*)(ws + (1024u << 10));        // 512 KB
    int*    idx   = (int*)  (ws + (1536u << 10));        // 512 KB
    int*    nnz   = (int*)  (ws + (2048u << 10));        //   1 KB

    k_prep  <<<1024, 256, 0, stream>>>(Wg1, wg1t, C_target, Wg2, bias, g,
                                       mask, idx, nnz);
    k_score <<<4096, 256, 0, stream>>>(C, wg1t, g, Wg0, idx, nnz, score);
    k_post  <<<256, 256, 0, stream>>>(score, mask, alpha, C, X, out);
}

// Round 4
// 592.626 us; speedup vs baseline: 1.3274x; 1.3274x over previous
//
#include <hip/hip_runtime.h>
#include <hip/hip_bf16.h>

typedef __bf16 bf16_t;
typedef bf16_t bf16x8 __attribute__((ext_vector_type(8)));
typedef float f32x4 __attribute__((ext_vector_type(4)));

#define AS1 __attribute__((address_space(1)))
#define AS3 __attribute__((address_space(3)))

// ---------------------------------------------------------------------------
// K_PREP: fused { Wg1 -> W3 repack (bf16, DMA-slot order), gate GEMV,
// mask compaction }. grid 896 x 256 thr, switched on blockIdx ranges.
//   W3 layout: W3[((k>>3)*512 + n)*8 + (k&7)] = (bf16)Wg1[k][n]
//   so chunk kc / q-slot i / col n is one contiguous 16B slot -> the k_score
//   B-stage is 4 perfectly-coalesced global_load_lds x16B per thread.
//   bid [0,128):    W3 repack (slot = bid*256+t; 8 coalesced reads, 1 x16B write)
//   bid [128,640):  g[b][e] = Ct[b,:]@Wg2[:,e]+bias
//   bid [640,896):  per-batch unmasked-row compaction (wave 0)
// ---------------------------------------------------------------------------
__global__ __launch_bounds__(256) void k_prep(const float* __restrict__ Wg1,
                                              bf16_t* __restrict__ W3,
                                              const float* __restrict__ Ct,
                                              const float* __restrict__ Wg2,
                                              const float* __restrict__ bias,
                                              float* __restrict__ g,
                                              const int* __restrict__ mask,
                                              int* __restrict__ idx,
                                              int* __restrict__ nnz) {
    const int bid = blockIdx.x;
    const int t   = threadIdx.x;
    if (bid < 128) {
        const int slot = bid * 256 + t;      // 0..32767 = K3*512 + n
        const int K3   = slot >> 9;
        const int n    = slot & 511;
        union { bf16_t h[8]; uint4 u; } pk;
        #pragma unroll
        for (int j = 0; j < 8; ++j)
            pk.h[j] = (bf16_t)Wg1[(K3 * 8 + j) * 512 + n];
        *reinterpret_cast<uint4*>(W3 + (size_t)slot * 8) = pk.u;
    } else if (bid < 640) {
        __shared__ float q[512];
        const int gb = bid - 128;
        const int b  = gb >> 1;
        q[t]       = Ct[b * 512 + t];
        q[t + 256] = Ct[b * 512 + t + 256];
        __syncthreads();
        const int e = ((gb & 1) << 8) + t;
        float acc = bias[e];
        #pragma unroll 16
        for (int k = 0; k < 512; ++k)
            acc = fmaf(q[k], Wg2[k * 512 + e], acc);
        g[b * 512 + e] = acc;
    } else {
        const int b = bid - 640;
        if (t < 64) {                        // wave 0 only
            const int lane = t;
            int base = 0;
            #pragma unroll
            for (int c = 0; c < 8; ++c) {
                const int l = (c << 6) + lane;
                const int v = mask[(b << 9) + l];
                const unsigned long long m = __ballot(v != 0);
                const int rank = __popcll(m & ((1ull << lane) - 1ull));
                if (v) idx[(b << 9) + base + rank] = l;
                base += __popcll(m);
            }
            if (lane == 0) nnz[b] = base;
        }
    }
}

// ---------------------------------------------------------------------------
// K2 v4: compacted-row GEMM, true 2-phase double-buffered DMA pipeline.
// Round-3 post-mortem: direct-from-global operands = pure L2-latency chain
// (MfmaUtil 3.9%). Fix per guide T3 "minimum 2-phase": stage chunk t+1 into
// buf^1 FIRST (4x global_load_lds for B from W3 + reg->ds_write for A, with
// A's global loads issued one full iteration ahead), THEN compute chunk t
// from buf; single vmcnt(0)+barrier per chunk, so staging has the whole
// MFMA+ds_read phase to land.
//   M=64 rows x N=256 (nh half) x Kc=32. acc[4][4]=64 AGPR (R1-proven,
//   no spill). LDS 41 KB -> 3 blocks/CU at __launch_bounds__(256,3).
//   Partial sums per nh go to scoreh[nh]; k_post adds them (no atomics).
// ---------------------------------------------------------------------------
__global__ __launch_bounds__(256, 3) void k_score(const float* __restrict__ C,
                                                  const bf16_t* __restrict__ W3,
                                                  const float* __restrict__ g,
                                                  const float* __restrict__ Wg0,
                                                  const int* __restrict__ idx,
                                                  const int* __restrict__ nnz,
                                                  float* __restrict__ scoreh) {
    __shared__ __align__(16) bf16_t Bs[2][4 * 256 * 8];  // 2 x 16 KB [q][nn][8]
    __shared__ __align__(16) bf16_t As[2][4 * 64 * 8];   // 2 x  4 KB [q][row][8]
    __shared__ float sred[4][64];

    const int t    = threadIdx.x;
    const int lane = t & 63;
    const int wave = t >> 6;
    const int quad = lane >> 4;
    const int l15  = lane & 15;

    const int bid  = blockIdx.x;        // 4096 = 256 b x 8 tiles x 2 nh
    const int nh   = bid & 1;
    const int tl   = bid >> 1;
    const int b    = tl >> 3;
    const int tile = tl & 7;
    const int nb   = nnz[b];
    if (tile * 64 >= nb) return;        // uniform early exit (before barriers)

    const int ncol0 = nh << 8;

    // A-staging assignment: thread owns (row = t&63, q = t>>6) = one 16B slot
    const int arow = t & 63;
    const int aq   = t >> 6;
    const int ja   = tile * 64 + arow;
    const int ra   = idx[(b << 9) + (ja < nb ? ja : nb - 1)];  // clamp: dup ok
    const float* Ca = C + ((size_t)b << 18) + (size_t)ra * 512 + aq * 8;

    // ---- prologue: stage chunk 0, prefetch A(1) regs ----
    float4 a0 = *reinterpret_cast<const float4*>(Ca);
    float4 a1 = *reinterpret_cast<const float4*>(Ca + 4);
    {
        union { bf16_t h[8]; uint4 u; } pk;
        pk.h[0] = (bf16_t)a0.x; pk.h[1] = (bf16_t)a0.y;
        pk.h[2] = (bf16_t)a0.z; pk.h[3] = (bf16_t)a0.w;
        pk.h[4] = (bf16_t)a1.x; pk.h[5] = (bf16_t)a1.y;
        pk.h[6] = (bf16_t)a1.z; pk.h[7] = (bf16_t)a1.w;
        *reinterpret_cast<uint4*>(&As[0][(aq * 64 + arow) * 8]) = pk.u;
    }
    a0 = *reinterpret_cast<const float4*>(Ca + 32);
    a1 = *reinterpret_cast<const float4*>(Ca + 36);
    #pragma unroll
    for (int i = 0; i < 4; ++i)
        __builtin_amdgcn_global_load_lds(
            (const AS1 void*)(W3 + ((size_t)(i * 512) + ncol0 + t) * 8),
            (AS3 void*)(&Bs[0][(i * 256 + t) * 8]), 16, 0, 0);
    __syncthreads();

    f32x4 acc[4][4] = {};

    #pragma unroll
    for (int kc = 0; kc < 16; ++kc) {
        const int c = kc & 1;
        // ---- stage chunk kc+1 into buf c^1 (issued BEFORE compute) ----
        if (kc < 15) {
            #pragma unroll
            for (int i = 0; i < 4; ++i)
                __builtin_amdgcn_global_load_lds(
                    (const AS1 void*)(W3 + ((size_t)((kc + 1) * 4 + i) * 512
                                            + ncol0 + t) * 8),
                    (AS3 void*)(&Bs[c ^ 1][(i * 256 + t) * 8]), 16, 0, 0);
            union { bf16_t h[8]; uint4 u; } pk;   // regs drained at last barrier
            pk.h[0] = (bf16_t)a0.x; pk.h[1] = (bf16_t)a0.y;
            pk.h[2] = (bf16_t)a0.z; pk.h[3] = (bf16_t)a0.w;
            pk.h[4] = (bf16_t)a1.x; pk.h[5] = (bf16_t)a1.y;
            pk.h[6] = (bf16_t)a1.z; pk.h[7] = (bf16_t)a1.w;
            *reinterpret_cast<uint4*>(&As[c ^ 1][(aq * 64 + arow) * 8]) = pk.u;
        }
        if (kc < 14) {                    // A regs for chunk kc+2
            a0 = *reinterpret_cast<const float4*>(Ca + (kc + 2) * 32);
            a1 = *reinterpret_cast<const float4*>(Ca + (kc + 2) * 32 + 4);
        }
        // ---- compute chunk kc from buf c ----
        bf16x8 afr[4], bfr[4];
        #pragma unroll
        for (int mi = 0; mi < 4; ++mi)
            afr[mi] = *reinterpret_cast<const bf16x8*>(
                &As[c][(quad * 64 + mi * 16 + l15) * 8]);
        #pragma unroll
        for (int ni = 0; ni < 4; ++ni)
            bfr[ni] = *reinterpret_cast<const bf16x8*>(
                &Bs[c][(quad * 256 + wave * 64 + ni * 16 + l15) * 8]);
        #pragma unroll
        for (int mi = 0; mi < 4; ++mi)
            #pragma unroll
            for (int ni = 0; ni < 4; ++ni)
                acc[mi][ni] = __builtin_amdgcn_mfma_f32_16x16x32_bf16(
                    afr[mi], bfr[ni], acc[mi][ni], 0, 0, 0);
        __syncthreads();   // drains DMA(kc+1)+A-loads(kc+2): full phase to land
    }

    // ---- epilogue: relu(u+g)*w0, reduce over this block's 256 n ----
    float rsum[16];
    #pragma unroll
    for (int i = 0; i < 16; ++i) rsum[i] = 0.f;
    #pragma unroll
    for (int ni = 0; ni < 4; ++ni) {
        const int n  = ncol0 + wave * 64 + ni * 16 + l15;   // D col = lane&15
        const float gv = g[(b << 9) + n];
        const float w0 = Wg0[n];
        #pragma unroll
        for (int mi = 0; mi < 4; ++mi)
            #pragma unroll
            for (int r = 0; r < 4; ++r) {            // D row = quad*4 + r
                const float u = fmaxf(acc[mi][ni][r] + gv, 0.f);
                rsum[mi * 4 + r] = fmaf(u, w0, rsum[mi * 4 + r]);
            }
    }
    #pragma unroll
    for (int i = 0; i < 16; ++i) {
        float v = rsum[i];
        v += __shfl_xor(v, 1);
        v += __shfl_xor(v, 2);
        v += __shfl_xor(v, 4);
        v += __shfl_xor(v, 8);
        rsum[i] = v;
    }
    if (l15 == 0) {
        #pragma unroll
        for (int mi = 0; mi < 4; ++mi)
            #pragma unroll
            for (int r = 0; r < 4; ++r)
                sred[wave][mi * 16 + quad * 4 + r] = rsum[mi * 4 + r];
    }
    __syncthreads();
    if (t < 64) {
        const int j = tile * 64 + t;
        if (j < nb) {
            const float sc = sred[0][t] + sred[1][t] + sred[2][t] + sred[3][t];
            scoreh[((size_t)nh << 17) + (b << 9) + idx[(b << 9) + j]] = sc;
        }
    }
}

// ---------------------------------------------------------------------------
// K_POST: fused { entmax bisection (wave 0), support-only attn, out GEMV }.
// One block per batch (256 blocks x 256 thr). Reads score = sh0 + sh1
// (the two n-half partials). No atomics, no memsets.
// ---------------------------------------------------------------------------
__global__ __launch_bounds__(256) void k_post(const float* __restrict__ scoreh,
                                              const int* __restrict__ mask,
                                              const float* __restrict__ alpha,
                                              const float* __restrict__ C,
                                              const float* __restrict__ X,
                                              float* __restrict__ out) {
    __shared__ float sup_v[512];
    __shared__ int   sup_i[512];
    __shared__ int   s_n;
    __shared__ float attn_s[512];
    __shared__ f32x4 red[4][64];

    const int b = blockIdx.x;
    const int t = threadIdx.x;

    // ---- phase 1: entmax on wave 0 (lane holds 8 scores) ----
    if (t < 64) {
        const int lane = t;
        const float am1 = alpha[0] - 1.0f;
        const float inv = 1.0f / am1;
        const bool  sq  = fabsf(inv - 2.0f) < 1e-6f;   // alpha==1.5 -> u*u
        const float neg = -1e30f * am1;

        const float* s0 = scoreh + (b << 9);
        const float* s1 = scoreh + (1u << 17) + (b << 9);
        const int*   mb = mask   + (b << 9);
        float x[8];
        {
            const float4 u0 = *reinterpret_cast<const float4*>(s0 + lane * 8);
            const float4 u1 = *reinterpret_cast<const float4*>(s0 + lane * 8 + 4);
            const float4 w0 = *reinterpret_cast<const float4*>(s1 + lane * 8);
            const float4 w1 = *reinterpret_cast<const float4*>(s1 + lane * 8 + 4);
            const int4   m0 = *reinterpret_cast<const int4*>(mb + lane * 8);
            const int4   m1 = *reinterpret_cast<const int4*>(mb + lane * 8 + 4);
            x[0] = m0.x ? (u0.x + w0.x) * am1 : neg;
            x[1] = m0.y ? (u0.y + w0.y) * am1 : neg;
            x[2] = m0.z ? (u0.z + w0.z) * am1 : neg;
            x[3] = m0.w ? (u0.w + w0.w) * am1 : neg;
            x[4] = m1.x ? (u1.x + w1.x) * am1 : neg;
            x[5] = m1.y ? (u1.y + w1.y) * am1 : neg;
            x[6] = m1.z ? (u1.z + w1.z) * am1 : neg;
            x[7] = m1.w ? (u1.w + w1.w) * am1 : neg;
        }
        float m = x[0];
        #pragma unroll
        for (int j = 1; j < 8; ++j) m = fmaxf(m, x[j]);
        #pragma unroll
        for (int s = 1; s < 64; s <<= 1) m = fmaxf(m, __shfl_xor(m, s));

        float tau_lo = m - 1.0f;
        float dm = (m - powf(1.0f / 512.0f, am1)) - tau_lo;

        float f_lo;
        {
            float s = 0.f;
            #pragma unroll
            for (int j = 0; j < 8; ++j) {
                const float u = fmaxf(x[j] - tau_lo, 0.f);
                s += sq ? u * u : powf(u, inv);
            }
            #pragma unroll
            for (int sh = 1; sh < 64; sh <<= 1) s += __shfl_xor(s, sh);
            f_lo = s - 1.0f;
        }
        for (int it = 0; it < 50; ++it) {
            dm *= 0.5f;
            const float tau_m = tau_lo + dm;
            float s = 0.f;
            #pragma unroll
            for (int j = 0; j < 8; ++j) {
                const float u = fmaxf(x[j] - tau_m, 0.f);
                s += sq ? u * u : powf(u, inv);
            }
            #pragma unroll
            for (int sh = 1; sh < 64; sh <<= 1) s += __shfl_xor(s, sh);
            if ((s - 1.0f) * f_lo >= 0.f) tau_lo = tau_m;
        }
        const float tau = tau_lo + 0.5f * dm;
        float pj[8];
        float Z = 0.f;
        #pragma unroll
        for (int j = 0; j < 8; ++j) {
            const float u = fmaxf(x[j] - tau, 0.f);
            pj[j] = sq ? u * u : powf(u, inv);
            Z += pj[j];
        }
        #pragma unroll
        for (int sh = 1; sh < 64; sh <<= 1) Z += __shfl_xor(Z, sh);
        const float rz = 1.0f / Z;

        int base = 0;
        #pragma unroll
        for (int j = 0; j < 8; ++j) {
            const float pv = pj[j] * rz;
            const unsigned long long bm = __ballot(pv > 0.f);
            const int rank = __popcll(bm & ((1ull << lane) - 1ull));
            if (pv > 0.f) {
                sup_i[base + rank] = lane * 8 + j;
                sup_v[base + rank] = pv;
            }
            base += __popcll(bm);
        }
        if (lane == 0) s_n = base;
    }
    __syncthreads();

    // ---- phase 2: attn[e] = sum_j pv[j] * C[b, li[j], e] (support only) ----
    const int n = s_n;
    const float* Cb = C + ((size_t)b << 18);
    float a0 = 0.f, a1 = 0.f;
    int j = 0;
    for (; j + 4 <= n; j += 4) {
        #pragma unroll
        for (int u = 0; u < 4; ++u) {
            const float  w  = sup_v[j + u];
            const float* cr = Cb + ((size_t)sup_i[j + u] << 9);
            a0 = fmaf(w, cr[t], a0);
            a1 = fmaf(w, cr[t + 256], a1);
        }
    }
    for (; j < n; ++j) {
        const float  w  = sup_v[j];
        const float* cr = Cb + ((size_t)sup_i[j] << 9);
        a0 = fmaf(w, cr[t], a0);
        a1 = fmaf(w, cr[t + 256], a1);
    }
    attn_s[t]       = a0;
    attn_s[t + 256] = a1;
    __syncthreads();

    // ---- phase 3: out[b][d] = sum_e attn[e] * X[b][e][d], stream 512KB ----
    const int eg = t >> 6;               // 0..3 e-interleave group
    const int d4 = t & 63;               // float4 slot over d
    const float4* Xb = reinterpret_cast<const float4*>(X + ((size_t)b << 17));
    f32x4 a = {};
    #pragma unroll 8
    for (int e = eg; e < 512; e += 4) {
        const float  w = attn_s[e];
        const float4 v = Xb[e * 64 + d4];
        a[0] = fmaf(w, v.x, a[0]);
        a[1] = fmaf(w, v.y, a[1]);
        a[2] = fmaf(w, v.z, a[2]);
        a[3] = fmaf(w, v.w, a[3]);
    }
    red[eg][d4] = a;
    __syncthreads();
    if (t < 64) {
        const f32x4 s = red[0][t] + red[1][t] + red[2][t] + red[3][t];
        float4 o;
        o.x = s[0]; o.y = s[1]; o.z = s[2]; o.w = s[3];
        *reinterpret_cast<float4*>(out + (b << 8) + (t << 2)) = o;
    }
}

// ---------------------------------------------------------------------------
extern "C" void kernel_launch(void* const* d_in, const int* in_sizes, int n_in,
                              void* d_out, int out_size, void* d_ws, size_t ws_size,
                              hipStream_t stream) {
    const float* C_target = (const float*)d_in[0];
    const float* C        = (const float*)d_in[1];
    const float* X        = (const float*)d_in[2];
    const float* alpha    = (const float*)d_in[3];
    const int*   mask     = (const int*)  d_in[4];
    const float* Wg1      = (const float*)d_in[5];
    const float* Wg2      = (const float*)d_in[6];
    const float* Wg0      = (const float*)d_in[7];
    const float* bias     = (const float*)d_in[8];
    float* out = (float*)d_out;

    char* ws = (char*)d_ws;
    bf16_t* w3     = (bf16_t*)(ws);                      // 512 KB
    float*  g      = (float*)(ws + ( 512u << 10));       // 512 KB
    float*  scoreh = (float*)(ws + (1024u << 10));       //   1 MB (2 halves)
    int*    idx    = (int*)  (ws + (2048u << 10));       // 512 KB
    int*    nnz    = (int*)  (ws + (2560u << 10));       //   1 KB

    k_prep  <<<896, 256, 0, stream>>>(Wg1, w3, C_target, Wg2, bias, g,
                                      mask, idx, nnz);
    k_score <<<4096, 256, 0, stream>>>(C, w3, g, Wg0, idx, nnz, scoreh);
    k_post  <<<256, 256, 0, stream>>>(scoreh, mask, alpha, C, X, out);
}

// Round 5
// 565.616 us; speedup vs baseline: 1.3908x; 1.0478x over previous
//
#include <hip/hip_runtime.h>
#include <hip/hip_bf16.h>

typedef __bf16 bf16_t;
typedef bf16_t bf16x8 __attribute__((ext_vector_type(8)));
typedef float f32x4 __attribute__((ext_vector_type(4)));

#define AS1 __attribute__((address_space(1)))
#define AS3 __attribute__((address_space(3)))

// ---------------------------------------------------------------------------
// K_PREP: fused { Wg1 -> W3 repack (bf16, DMA-slot order), gate GEMV,
// mask compaction }. grid 896 x 256 thr, switched on blockIdx ranges.
//   W3 layout: W3[((k>>3)*512 + n)*8 + (k&7)] = (bf16)Wg1[k][n]
// ---------------------------------------------------------------------------
__global__ __launch_bounds__(256) void k_prep(const float* __restrict__ Wg1,
                                              bf16_t* __restrict__ W3,
                                              const float* __restrict__ Ct,
                                              const float* __restrict__ Wg2,
                                              const float* __restrict__ bias,
                                              float* __restrict__ g,
                                              const int* __restrict__ mask,
                                              int* __restrict__ idx,
                                              int* __restrict__ nnz) {
    const int bid = blockIdx.x;
    const int t   = threadIdx.x;
    if (bid < 128) {
        const int slot = bid * 256 + t;      // 0..32767 = K3*512 + n
        const int K3   = slot >> 9;
        const int n    = slot & 511;
        union { bf16_t h[8]; uint4 u; } pk;
        #pragma unroll
        for (int j = 0; j < 8; ++j)
            pk.h[j] = (bf16_t)Wg1[(K3 * 8 + j) * 512 + n];
        *reinterpret_cast<uint4*>(W3 + (size_t)slot * 8) = pk.u;
    } else if (bid < 640) {
        __shared__ float q[512];
        const int gb = bid - 128;
        const int b  = gb >> 1;
        q[t]       = Ct[b * 512 + t];
        q[t + 256] = Ct[b * 512 + t + 256];
        __syncthreads();
        const int e = ((gb & 1) << 8) + t;
        float acc = bias[e];
        #pragma unroll 16
        for (int k = 0; k < 512; ++k)
            acc = fmaf(q[k], Wg2[k * 512 + e], acc);
        g[b * 512 + e] = acc;
    } else {
        const int b = bid - 640;
        if (t < 64) {                        // wave 0 only
            const int lane = t;
            int base = 0;
            #pragma unroll
            for (int c = 0; c < 8; ++c) {
                const int l = (c << 6) + lane;
                const int v = mask[(b << 9) + l];
                const unsigned long long m = __ballot(v != 0);
                const int rank = __popcll(m & ((1ull << lane) - 1ull));
                if (v) idx[(b << 9) + base + rank] = l;
                base += __popcll(m);
            }
            if (lane == 0) nnz[b] = base;
        }
    }
}

// ---------------------------------------------------------------------------
// K2 v5: counted-vmcnt raw-barrier pipeline (guide T4).
// Round-4 post-mortem: __syncthreads drains vmcnt(0) each chunk -> every
// chunk exposes the HBM A-gather latency at the barrier. Fix:
//   - A is WAVE-PRIVATE in registers (wave owns 16 rows; lane gathers its
//     fragment rows directly from C, cvt fp32->bf16 in regs). No A in LDS,
//     so the barrier has nothing to guard for A.
//   - Per chunk: [cvt A(kc)] [4x global_load_lds B(kc+1)] [A loads kc+2]
//     [16 ds_read+MFMA] [lgkmcnt(0); vmcnt(2); s_barrier]. vmcnt retires
//     in order: <=2 outstanding => all 4 DMAs landed, while the 2 newest
//     A loads STAY IN FLIGHT across the barrier (~2 phases of HBM cover).
//   - sched_barrier(0) fences pin issue order (DMA before A loads; nothing
//     crosses the sync) so the asm vmcnt count is exact.
//   - Wave w computes rows [w*16,w*16+16) x 256 cols (nh half);
//     acc[16] = 64 AGPR. LDS = 2x16 KB B double-buffer only.
//   - Epilogue: rows are wave-disjoint -> no cross-wave reduce; lane l15==0
//     stores 4 rows directly to scoreh[nh] (partials summed in k_post).
// ---------------------------------------------------------------------------
__global__ __launch_bounds__(256, 3) void k_score(const float* __restrict__ C,
                                                  const bf16_t* __restrict__ W3,
                                                  const float* __restrict__ g,
                                                  const float* __restrict__ Wg0,
                                                  const int* __restrict__ idx,
                                                  const int* __restrict__ nnz,
                                                  float* __restrict__ scoreh) {
    __shared__ __align__(16) bf16_t Bs[2][4 * 256 * 8];  // 2 x 16 KB [q][col][8]

    const int t    = threadIdx.x;
    const int lane = t & 63;
    const int wave = t >> 6;
    const int quad = lane >> 4;
    const int l15  = lane & 15;

    const int bid  = blockIdx.x;        // 4096 = 256 b x 8 tiles x 2 nh
    const int nh   = bid & 1;
    const int tl   = bid >> 1;
    const int b    = tl >> 3;
    const int tile = tl & 7;
    const int nb   = nnz[b];
    if (tile * 64 >= nb) return;        // uniform early exit (before barriers)

    const int ncol0 = nh << 8;

    // wave-private A row for this lane: row-in-block = wave*16 + l15
    const int ja = tile * 64 + wave * 16 + l15;
    const int ra = idx[(b << 9) + (ja < nb ? ja : nb - 1)];  // clamp: dup ok
    const float* Ca = C + ((size_t)b << 18) + (size_t)ra * 512 + (quad << 3);

    // ---- prologue: DMA B(0), then A(0),A(1) loads, counted sync ----
    #pragma unroll
    for (int i = 0; i < 4; ++i)
        __builtin_amdgcn_global_load_lds(
            (const AS1 void*)(W3 + ((size_t)i * 512 + ncol0 + t) * 8),
            (AS3 void*)(&Bs[0][(i * 256 + t) * 8]), 16, 0, 0);
    __builtin_amdgcn_sched_barrier(0);
    float4 va[2][2];
    va[0][0] = *reinterpret_cast<const float4*>(Ca);
    va[0][1] = *reinterpret_cast<const float4*>(Ca + 4);
    va[1][0] = *reinterpret_cast<const float4*>(Ca + 32);
    va[1][1] = *reinterpret_cast<const float4*>(Ca + 36);
    __builtin_amdgcn_sched_barrier(0);
    asm volatile("s_waitcnt vmcnt(4)" ::: "memory");   // B(0) landed; A in flight
    __builtin_amdgcn_s_barrier();
    __builtin_amdgcn_sched_barrier(0);

    f32x4 acc[16] = {};

    #pragma unroll
    for (int kc = 0; kc < 16; ++kc) {
        const int c = kc & 1;
        // ---- cvt A(kc) from regs (loaded 2 chunks ago, drained by sync) ----
        union { bf16_t h[8]; bf16x8 v; } ua;
        {
            const float4 A0 = va[c][0], A1 = va[c][1];
            ua.h[0] = (bf16_t)A0.x; ua.h[1] = (bf16_t)A0.y;
            ua.h[2] = (bf16_t)A0.z; ua.h[3] = (bf16_t)A0.w;
            ua.h[4] = (bf16_t)A1.x; ua.h[5] = (bf16_t)A1.y;
            ua.h[6] = (bf16_t)A1.z; ua.h[7] = (bf16_t)A1.w;
        }
        __builtin_amdgcn_sched_barrier(0);
        // ---- issue B-DMA(kc+1) FIRST (oldest), then A loads (newest) ----
        if (kc < 15) {
            #pragma unroll
            for (int i = 0; i < 4; ++i)
                __builtin_amdgcn_global_load_lds(
                    (const AS1 void*)(W3 + ((size_t)((kc + 1) * 4 + i) * 512
                                            + ncol0 + t) * 8),
                    (AS3 void*)(&Bs[c ^ 1][(i * 256 + t) * 8]), 16, 0, 0);
        }
        __builtin_amdgcn_sched_barrier(0);
        if (kc < 14) {
            va[c][0] = *reinterpret_cast<const float4*>(Ca + (kc + 2) * 32);
            va[c][1] = *reinterpret_cast<const float4*>(Ca + (kc + 2) * 32 + 4);
        }
        __builtin_amdgcn_sched_barrier(0);
        // ---- compute chunk kc: 2 groups of {8 ds_read, 8 MFMA} ----
        #pragma unroll
        for (int g2 = 0; g2 < 2; ++g2) {
            bf16x8 bfr[8];
            #pragma unroll
            for (int ni = 0; ni < 8; ++ni)
                bfr[ni] = *reinterpret_cast<const bf16x8*>(
                    &Bs[c][(quad * 256 + (g2 * 8 + ni) * 16 + l15) * 8]);
            #pragma unroll
            for (int ni = 0; ni < 8; ++ni)
                acc[g2 * 8 + ni] = __builtin_amdgcn_mfma_f32_16x16x32_bf16(
                    ua.v, bfr[ni], acc[g2 * 8 + ni], 0, 0, 0);
        }
        // ---- counted sync: B(kc+1) landed, A loads stay in flight ----
        if (kc < 14) {
            __builtin_amdgcn_sched_barrier(0);
            asm volatile("s_waitcnt lgkmcnt(0)" ::: "memory");
            asm volatile("s_waitcnt vmcnt(2)" ::: "memory");
            __builtin_amdgcn_s_barrier();
            __builtin_amdgcn_sched_barrier(0);
        } else if (kc == 14) {
            __builtin_amdgcn_sched_barrier(0);
            asm volatile("s_waitcnt lgkmcnt(0)" ::: "memory");
            asm volatile("s_waitcnt vmcnt(0)" ::: "memory");
            __builtin_amdgcn_s_barrier();
            __builtin_amdgcn_sched_barrier(0);
        }
    }

    // ---- epilogue: relu(u+g)*w0, reduce over this wave's 256 n ----
    // acc[ni][r]: n = ncol0 + ni*16 + l15, row-in-block = wave*16 + quad*4 + r
    float rsum[4] = {0.f, 0.f, 0.f, 0.f};
    #pragma unroll
    for (int ni = 0; ni < 16; ++ni) {
        const int n  = ncol0 + (ni << 4) + l15;
        const float gv = g[(b << 9) + n];
        const float w0 = Wg0[n];
        #pragma unroll
        for (int r = 0; r < 4; ++r) {
            const float u = fmaxf(acc[ni][r] + gv, 0.f);
            rsum[r] = fmaf(u, w0, rsum[r]);
        }
    }
    #pragma unroll
    for (int r = 0; r < 4; ++r) {
        float v = rsum[r];
        v += __shfl_xor(v, 1);
        v += __shfl_xor(v, 2);
        v += __shfl_xor(v, 4);
        v += __shfl_xor(v, 8);
        rsum[r] = v;
    }
    if (l15 == 0) {
        #pragma unroll
        for (int r = 0; r < 4; ++r) {
            const int j = tile * 64 + wave * 16 + quad * 4 + r;
            if (j < nb)
                scoreh[((size_t)nh << 17) + (b << 9) + idx[(b << 9) + j]]
                    = rsum[r];
        }
    }
}

// ---------------------------------------------------------------------------
// K_POST: fused { entmax bisection (wave 0), support-only attn, out GEMV }.
// One block per batch (256 blocks x 256 thr). Reads score = sh0 + sh1
// (the two n-half partials). No atomics, no memsets.
// ---------------------------------------------------------------------------
__global__ __launch_bounds__(256) void k_post(const float* __restrict__ scoreh,
                                              const int* __restrict__ mask,
                                              const float* __restrict__ alpha,
                                              const float* __restrict__ C,
                                              const float* __restrict__ X,
                                              float* __restrict__ out) {
    __shared__ float sup_v[512];
    __shared__ int   sup_i[512];
    __shared__ int   s_n;
    __shared__ float attn_s[512];
    __shared__ f32x4 red[4][64];

    const int b = blockIdx.x;
    const int t = threadIdx.x;

    // ---- phase 1: entmax on wave 0 (lane holds 8 scores) ----
    if (t < 64) {
        const int lane = t;
        const float am1 = alpha[0] - 1.0f;
        const float inv = 1.0f / am1;
        const bool  sq  = fabsf(inv - 2.0f) < 1e-6f;   // alpha==1.5 -> u*u
        const float neg = -1e30f * am1;

        const float* s0 = scoreh + (b << 9);
        const float* s1 = scoreh + (1u << 17) + (b << 9);
        const int*   mb = mask   + (b << 9);
        float x[8];
        {
            const float4 u0 = *reinterpret_cast<const float4*>(s0 + lane * 8);
            const float4 u1 = *reinterpret_cast<const float4*>(s0 + lane * 8 + 4);
            const float4 w0 = *reinterpret_cast<const float4*>(s1 + lane * 8);
            const float4 w1 = *reinterpret_cast<const float4*>(s1 + lane * 8 + 4);
            const int4   m0 = *reinterpret_cast<const int4*>(mb + lane * 8);
            const int4   m1 = *reinterpret_cast<const int4*>(mb + lane * 8 + 4);
            x[0] = m0.x ? (u0.x + w0.x) * am1 : neg;
            x[1] = m0.y ? (u0.y + w0.y) * am1 : neg;
            x[2] = m0.z ? (u0.z + w0.z) * am1 : neg;
            x[3] = m0.w ? (u0.w + w0.w) * am1 : neg;
            x[4] = m1.x ? (u1.x + w1.x) * am1 : neg;
            x[5] = m1.y ? (u1.y + w1.y) * am1 : neg;
            x[6] = m1.z ? (u1.z + w1.z) * am1 : neg;
            x[7] = m1.w ? (u1.w + w1.w) * am1 : neg;
        }
        float m = x[0];
        #pragma unroll
        for (int j = 1; j < 8; ++j) m = fmaxf(m, x[j]);
        #pragma unroll
        for (int s = 1; s < 64; s <<= 1) m = fmaxf(m, __shfl_xor(m, s));

        float tau_lo = m - 1.0f;
        float dm = (m - powf(1.0f / 512.0f, am1)) - tau_lo;

        float f_lo;
        {
            float s = 0.f;
            #pragma unroll
            for (int j = 0; j < 8; ++j) {
                const float u = fmaxf(x[j] - tau_lo, 0.f);
                s += sq ? u * u : powf(u, inv);
            }
            #pragma unroll
            for (int sh = 1; sh < 64; sh <<= 1) s += __shfl_xor(s, sh);
            f_lo = s - 1.0f;
        }
        for (int it = 0; it < 50; ++it) {
            dm *= 0.5f;
            const float tau_m = tau_lo + dm;
            float s = 0.f;
            #pragma unroll
            for (int j = 0; j < 8; ++j) {
                const float u = fmaxf(x[j] - tau_m, 0.f);
                s += sq ? u * u : powf(u, inv);
            }
            #pragma unroll
            for (int sh = 1; sh < 64; sh <<= 1) s += __shfl_xor(s, sh);
            if ((s - 1.0f) * f_lo >= 0.f) tau_lo = tau_m;
        }
        const float tau = tau_lo + 0.5f * dm;
        float pj[8];
        float Z = 0.f;
        #pragma unroll
        for (int j = 0; j < 8; ++j) {
            const float u = fmaxf(x[j] - tau, 0.f);
            pj[j] = sq ? u * u : powf(u, inv);
            Z += pj[j];
        }
        #pragma unroll
        for (int sh = 1; sh < 64; sh <<= 1) Z += __shfl_xor(Z, sh);
        const float rz = 1.0f / Z;

        int base = 0;
        #pragma unroll
        for (int j = 0; j < 8; ++j) {
            const float pv = pj[j] * rz;
            const unsigned long long bm = __ballot(pv > 0.f);
            const int rank = __popcll(bm & ((1ull << lane) - 1ull));
            if (pv > 0.f) {
                sup_i[base + rank] = lane * 8 + j;
                sup_v[base + rank] = pv;
            }
            base += __popcll(bm);
        }
        if (lane == 0) s_n = base;
    }
    __syncthreads();

    // ---- phase 2: attn[e] = sum_j pv[j] * C[b, li[j], e] (support only) ----
    const int n = s_n;
    const float* Cb = C + ((size_t)b << 18);
    float a0 = 0.f, a1 = 0.f;
    int j = 0;
    for (; j + 4 <= n; j += 4) {
        #pragma unroll
        for (int u = 0; u < 4; ++u) {
            const float  w  = sup_v[j + u];
            const float* cr = Cb + ((size_t)sup_i[j + u] << 9);
            a0 = fmaf(w, cr[t], a0);
            a1 = fmaf(w, cr[t + 256], a1);
        }
    }
    for (; j < n; ++j) {
        const float  w  = sup_v[j];
        const float* cr = Cb + ((size_t)sup_i[j] << 9);
        a0 = fmaf(w, cr[t], a0);
        a1 = fmaf(w, cr[t + 256], a1);
    }
    attn_s[t]       = a0;
    attn_s[t + 256] = a1;
    __syncthreads();

    // ---- phase 3: out[b][d] = sum_e attn[e] * X[b][e][d], stream 512KB ----
    const int eg = t >> 6;               // 0..3 e-interleave group
    const int d4 = t & 63;               // float4 slot over d
    const float4* Xb = reinterpret_cast<const float4*>(X + ((size_t)b << 17));
    f32x4 a = {};
    #pragma unroll 8
    for (int e = eg; e < 512; e += 4) {
        const float  w = attn_s[e];
        const float4 v = Xb[e * 64 + d4];
        a[0] = fmaf(w, v.x, a[0]);
        a[1] = fmaf(w, v.y, a[1]);
        a[2] = fmaf(w, v.z, a[2]);
        a[3] = fmaf(w, v.w, a[3]);
    }
    red[eg][d4] = a;
    __syncthreads();
    if (t < 64) {
        const f32x4 s = red[0][t] + red[1][t] + red[2][t] + red[3][t];
        float4 o;
        o.x = s[0]; o.y = s[1]; o.z = s[2]; o.w = s[3];
        *reinterpret_cast<float4*>(out + (b << 8) + (t << 2)) = o;
    }
}

// ---------------------------------------------------------------------------
extern "C" void kernel_launch(void* const* d_in, const int* in_sizes, int n_in,
                              void* d_out, int out_size, void* d_ws, size_t ws_size,
                              hipStream_t stream) {
    const float* C_target = (const float*)d_in[0];
    const float* C        = (const float*)d_in[1];
    const float* X        = (const float*)d_in[2];
    const float* alpha    = (const float*)d_in[3];
    const int*   mask     = (const int*)  d_in[4];
    const float* Wg1      = (const float*)d_in[5];
    const float* Wg2      = (const float*)d_in[6];
    const float* Wg0      = (const float*)d_in[7];
    const float* bias     = (const float*)d_in[8];
    float* out = (float*)d_out;

    char* ws = (char*)d_ws;
    bf16_t* w3     = (bf16_t*)(ws);                      // 512 KB
    float*  g      = (float*)(ws + ( 512u << 10));       // 512 KB
    float*  scoreh = (float*)(ws + (1024u << 10));       //   1 MB (2 halves)
    int*    idx    = (int*)  (ws + (2048u << 10));       // 512 KB
    int*    nnz    = (int*)  (ws + (2560u << 10));       //   1 KB

    k_prep  <<<896, 256, 0, stream>>>(Wg1, w3, C_target, Wg2, bias, g,
                                      mask, idx, nnz);
    k_score <<<4096, 256, 0, stream>>>(C, w3, g, Wg0, idx, nnz, scoreh);
    k_post  <<<256, 256, 0, stream>>>(scoreh, mask, alpha, C, X, out);
}